// Round 2
// baseline (1568.866 us; speedup 1.0000x reference)
//
#include <hip/hip_runtime.h>
#include <cstdint>

#define T_ 4
#define B_ 16
#define C_ 384
#define N_ 1024
#define CN (C_*N_)             // 393216
#define BCN (B_*CN)            // 6291456
#define EPS 1e-5f
#define QS 17                  // per-o LDS column stride (16 n-slots + 1 pad, odd => conflict-free)

// workspace layout (bytes)
#define WQT_OFF   0u           // 384*384*4 = 589824
#define WPT_OFF   589824u
#define QINV_OFF  1179648u
#define QOFF_OFF  (QINV_OFF + 1536u)
#define PINV_OFF  (QINV_OFF + 3072u)
#define POFF_OFF  (QINV_OFF + 4608u)
#define C0_OFF    (QINV_OFF + 6144u)
#define XM_OFF    2097152u     // u64[4][16][16][384] = 3145728 B
#define MS_OFF    6291456u     // u64[4][16][16][384] (written as u16 quarters), ends 9437184

// ---------------- K0a: transpose wq, wp into ws ----------------
__global__ __launch_bounds__(256) void k0_transpose(const float* __restrict__ wq,
                                                    const float* __restrict__ wp,
                                                    char* __restrict__ ws) {
    int bid = blockIdx.x;
    const float* src = (bid < 576) ? wq : wp;
    float* dst = (float*)(ws + ((bid < 576) ? WQT_OFF : WPT_OFF));
    int i = (bid % 576) * 256 + threadIdx.x;     // 0..147455
    int c = i / 384, o = i % 384;
    dst[c * 384 + o] = src[o * 384 + c];
}

// ---------------- K0b: BN constants ----------------
__global__ void k0_consts(const float* __restrict__ qg, const float* __restrict__ qb,
                          const float* __restrict__ qm, const float* __restrict__ qv,
                          const float* __restrict__ pg, const float* __restrict__ pb,
                          const float* __restrict__ pm, const float* __restrict__ pv,
                          const float* __restrict__ bp, char* __restrict__ ws) {
    int i = threadIdx.x;                         // 384 threads
    float qi = qg[i] / sqrtf(qv[i] + EPS);
    ((float*)(ws + QINV_OFF))[i] = qi;
    ((float*)(ws + QOFF_OFF))[i] = qb[i] - qm[i] * qi;
    float pi = pg[i] / sqrtf(pv[i] + EPS);
    float po = pb[i] - pm[i] * pi;
    ((float*)(ws + PINV_OFF))[i] = pi;
    ((float*)(ws + POFF_OFF))[i] = po;
    ((float*)(ws + C0_OFF))[i] = bp[i] * pi + po;   // output value when GEMM2 input is all-zero
}

// ---------------- K1: shortcut LIF -> spike bitmasks ----------------
// wave w = (b, g, c); lane = n within 64-group; ballot packs spikes over n.
__global__ __launch_bounds__(256) void k1_lif(const float* __restrict__ x,
                                              unsigned long long* __restrict__ xm) {
    int wid  = (blockIdx.x * 256 + threadIdx.x) >> 6;   // 0..98303
    int lane = threadIdx.x & 63;
    int c = wid % 384;
    int g = (wid / 384) & 15;
    int b = wid / (384 * 16);
    const float* xp = x + (size_t)b * CN + (size_t)c * N_ + g * 64 + lane;
    float v = 0.f;
    #pragma unroll
    for (int t = 0; t < 4; ++t) {
        float xv = xp[(size_t)t * BCN];
        float h = v + (xv - v) * 0.5f;                  // v + (x - v)/tau, tau = 2
        bool s = (h >= 1.0f);
        unsigned long long m = __ballot(s);
        v = s ? 0.f : h;
        if (lane == 0) xm[(((size_t)t * 16 + b) * 16 + g) * 384 + c] = m;
    }
}

// ---------------- K2: sparse scatter GEMM1 + BN + q-LIF + attn mask ----------------
// block = (b, g, nh): 384 threads, thread owns output channel o = tid.
// LDS q[o][16]: thread-private dynamically-indexed accumulator.
// Scatter via fire-and-forget ds_add_f32 (no CAS, no waits, no barriers at all).
__global__ __launch_bounds__(384, 4) void k2_qpath(const float* __restrict__ wqT,
                                                   const float* __restrict__ qinv_,
                                                   const float* __restrict__ qoff_,
                                                   const unsigned long long* __restrict__ xm,
                                                   const unsigned char* __restrict__ ak,
                                                   const unsigned char* __restrict__ av,
                                                   unsigned short* __restrict__ ms) {
    __shared__ float q[384 * QS];                // 26112 B -> 4 blocks/CU
    const int tid = threadIdx.x;                 // output channel o
    const int bid = blockIdx.x;
    const int nh  = bid & 3;                     // 16-column n-slice
    const int g   = (bid >> 2) & 15;
    const int b   = bid >> 6;
    const int shift = nh << 4;
    const float qi = qinv_[tid], qo = qoff_[tid];
    const uint32_t qbase = (uint32_t)(uintptr_t)(&q[0]) + (uint32_t)tid * (QS * 4);
    float vq[16];
    #pragma unroll
    for (int n = 0; n < 16; ++n) vq[n] = 0.f;

    for (int t = 0; t < 4; ++t) {
        #pragma unroll
        for (int n = 0; n < 16; ++n) q[tid * QS + n] = 0.f;
        asm volatile("" ::: "memory");           // zero-stores stay above the asm adds
        const unsigned long long* xmt = xm + (((size_t)t * 16 + b) * 16 + g) * 384;
        for (int c0 = 0; c0 < 384; c0 += 8) {
            float w[8];
            #pragma unroll
            for (int u = 0; u < 8; ++u) {
                w[u] = wqT[(c0 + u) * 384 + tid];
                asm volatile("" : "+v"(w[u]));   // pin the 8 loads in flight here
            }
            #pragma unroll
            for (int u = 0; u < 8; ++u) {
                uint32_t m = (uint32_t)(xmt[c0 + u] >> shift) & 0xFFFFu;
                while (m) {
                    const uint32_t j = __builtin_ctz(m);
                    m &= m - 1;
                    asm volatile("ds_add_f32 %0, %1"
                                 :: "v"(qbase + (j << 2)), "v"(w[u]));
                }
            }
        }
        asm volatile("s_waitcnt lgkmcnt(0)" ::: "memory");  // drain scatter (rule #18)
        __builtin_amdgcn_sched_barrier(0);
        unsigned int msk = 0;
        #pragma unroll
        for (int n = 0; n < 16; ++n) {
            const float qbn = q[tid * QS + n] * qi + qo;
            const float h = vq[n] + (qbn - vq[n]) * 0.5f;
            bool s = (h >= 1.0f);
            vq[n] = s ? 0.f : h;
            if (s) {  // rare: only touch attention masks where a q-spike exists
                const size_t idx = ((((size_t)t * 16 + b) * 384 + tid) << 10)
                                   + (g << 6) + (nh << 4) + n;
                s = (ak[idx] != 0) && (av[idx] != 0);
            }
            msk |= (s ? 1u : 0u) << n;
        }
        ms[((((size_t)t * 16 + b) * 16 + g) * 384 + tid) * 4 + nh] = (unsigned short)msk;
        asm volatile("" ::: "memory");           // epilogue reads stay above next-t zeroing
    }
}

// ---------------- K3: proj GEMM2 + bias + BN ----------------
// block = (t, b, g); fast path when the masked-spike tile is all-zero.
__global__ __launch_bounds__(384) void k3_proj(const float* __restrict__ wpT,
                                               const float* __restrict__ pinv_,
                                               const float* __restrict__ poff_,
                                               const float* __restrict__ bp,
                                               const float* __restrict__ c0,
                                               const unsigned long long* __restrict__ ms,
                                               float* __restrict__ out) {
    __shared__ __align__(16) float q[64 * 200];
    __shared__ unsigned long long mk[384];
    __shared__ int anyflag;
    int tid = threadIdx.x;
    int bid = blockIdx.x;
    int g = bid & 15, b = (bid >> 4) & 15, t = bid >> 8;
    if (tid == 0) anyflag = 0;
    unsigned long long m = ms[(((size_t)t * 16 + b) * 16 + g) * 384 + tid];
    mk[tid] = m;
    __syncthreads();
    if (m) anyflag = 1;        // benign race: all writers store 1
    __syncthreads();
    size_t obase = ((size_t)t * 16 + b) * 384;

    if (!anyflag) {
        // all-zero GEMM2 input: out = bp*inv + off, coalesced float4 stores
        #pragma unroll
        for (int k = 0; k < 16; ++k) {
            int i = tid + k * 384;            // 0..6143 float4 units in the (384o x 64n) tile
            int o = i >> 4, n4 = i & 15;
            float v = c0[o];
            float4* dst = (float4*)out + (obase + o) * 256 + g * 16 + n4;
            *dst = make_float4(v, v, v, v);
        }
        return;
    }
    // slow path (never taken on the bench input, correct in general)
    for (int half = 0; half < 2; ++half) {
        __syncthreads();
        for (int i = tid * 4; i < 12800; i += 384 * 4)
            *(float4*)(q + i) = make_float4(0.f, 0.f, 0.f, 0.f);
        __syncthreads();
        int active = (tid >= half * 192) && (tid < half * 192 + 192);
        int col = tid - half * 192;
        if (active) {
            for (int c = 0; c < 384; ++c) {
                unsigned long long mm = mk[c];
                if (mm) {
                    float w = wpT[c * 384 + tid];
                    do {
                        int j = __builtin_ctzll(mm);
                        mm &= mm - 1;
                        atomicAdd(&q[j * 200 + col], w);
                    } while (mm);
                }
            }
        }
        __syncthreads();
        if (active) {
            float pi = pinv_[tid], po = poff_[tid], bpo = bp[tid];
            for (int n = 0; n < 64; ++n) {
                float val = (q[n * 200 + col] + bpo) * pi + po;
                out[(obase + tid) * 1024 + (size_t)g * 64 + n] = val;
            }
        }
    }
}

extern "C" void kernel_launch(void* const* d_in, const int* in_sizes, int n_in,
                              void* d_out, int out_size, void* d_ws, size_t ws_size,
                              hipStream_t stream) {
    const float* x  = (const float*)d_in[0];
    const unsigned char* ak = (const unsigned char*)d_in[1];
    const unsigned char* av = (const unsigned char*)d_in[2];
    const float* wq = (const float*)d_in[3];
    const float* qg = (const float*)d_in[4];
    const float* qb = (const float*)d_in[5];
    const float* qm = (const float*)d_in[6];
    const float* qv = (const float*)d_in[7];
    const float* wp = (const float*)d_in[8];
    const float* bp = (const float*)d_in[9];
    const float* pg = (const float*)d_in[10];
    const float* pb = (const float*)d_in[11];
    const float* pm = (const float*)d_in[12];
    const float* pv = (const float*)d_in[13];
    char* ws = (char*)d_ws;
    float* out = (float*)d_out;

    hipLaunchKernelGGL(k0_transpose, dim3(1152), dim3(256), 0, stream, wq, wp, ws);
    hipLaunchKernelGGL(k0_consts, dim3(1), dim3(384), 0, stream,
                       qg, qb, qm, qv, pg, pb, pm, pv, bp, ws);
    hipLaunchKernelGGL(k1_lif, dim3(24576), dim3(256), 0, stream,
                       x, (unsigned long long*)(ws + XM_OFF));
    hipLaunchKernelGGL(k2_qpath, dim3(1024), dim3(384), 0, stream,
                       (const float*)(ws + WQT_OFF), (const float*)(ws + QINV_OFF),
                       (const float*)(ws + QOFF_OFF),
                       (const unsigned long long*)(ws + XM_OFF), ak, av,
                       (unsigned short*)(ws + MS_OFF));
    hipLaunchKernelGGL(k3_proj, dim3(1024), dim3(384), 0, stream,
                       (const float*)(ws + WPT_OFF), (const float*)(ws + PINV_OFF),
                       (const float*)(ws + POFF_OFF), bp, (const float*)(ws + C0_OFF),
                       (const unsigned long long*)(ws + MS_OFF), out);
}

// Round 3
// 196.183 us; speedup vs baseline: 7.9970x; 7.9970x over previous
//
#include <hip/hip_runtime.h>
#include <cstdint>

#define CN (384*1024)          // 393216
#define BCN (16*CN)            // 6291456
#define EPS 1e-5f

// workspace layout (bytes)
#define WQT_OFF   0u           // f32[384][384] = 589824
#define WPT_OFF   589824u
#define QINV_OFF  1179648u
#define QOFF_OFF  (QINV_OFF + 1536u)
#define PINV_OFF  (QINV_OFF + 3072u)
#define POFF_OFF  (QINV_OFF + 4608u)
#define C0_OFF    (QINV_OFF + 6144u)
#define XM_OFF    2097152u     // u64[4][16][16][384] n-packed spikes, 3145728 B (ends 5242880)
#define XMT_OFF   5242880u     // u64[4][16][1024][6] c-packed spikes, 3145728 B (ends 8388608)
#define MST_OFF   XM_OFF       // masked q-spikes, c-packed; reuses xm (dead after k1b)

// ---------------- K0a: transpose wq, wp into ws ----------------
__global__ __launch_bounds__(256) void k0_transpose(const float* __restrict__ wq,
                                                    const float* __restrict__ wp,
                                                    char* __restrict__ ws) {
    int bid = blockIdx.x;
    const float* src = (bid < 576) ? wq : wp;
    float* dst = (float*)(ws + ((bid < 576) ? WQT_OFF : WPT_OFF));
    int i = (bid % 576) * 256 + threadIdx.x;     // 0..147455
    int c = i / 384, o = i % 384;
    dst[c * 384 + o] = src[o * 384 + c];
}

// ---------------- K0b: BN constants ----------------
__global__ void k0_consts(const float* __restrict__ qg, const float* __restrict__ qb,
                          const float* __restrict__ qm, const float* __restrict__ qv,
                          const float* __restrict__ pg, const float* __restrict__ pb,
                          const float* __restrict__ pm, const float* __restrict__ pv,
                          const float* __restrict__ bp, char* __restrict__ ws) {
    int i = threadIdx.x;                         // 384 threads
    float qi = qg[i] / sqrtf(qv[i] + EPS);
    ((float*)(ws + QINV_OFF))[i] = qi;
    ((float*)(ws + QOFF_OFF))[i] = qb[i] - qm[i] * qi;
    float pi = pg[i] / sqrtf(pv[i] + EPS);
    float po = pb[i] - pm[i] * pi;
    ((float*)(ws + PINV_OFF))[i] = pi;
    ((float*)(ws + POFF_OFF))[i] = po;
    ((float*)(ws + C0_OFF))[i] = bp[i] * pi + po;   // output value when GEMM2 input is all-zero
}

// ---------------- K1: shortcut LIF -> n-packed spike bitmasks ----------------
// wave = (b, g, c); lane = n within 64-group; ballot packs spikes over n.
__global__ __launch_bounds__(256) void k1_lif(const float* __restrict__ x,
                                              unsigned long long* __restrict__ xm) {
    int wid  = (blockIdx.x * 256 + threadIdx.x) >> 6;   // 0..98303
    int lane = threadIdx.x & 63;
    int c = wid % 384;
    int g = (wid / 384) & 15;
    int b = wid / (384 * 16);
    const float* xp = x + (size_t)b * CN + (size_t)c * 1024 + g * 64 + lane;
    float v = 0.f;
    #pragma unroll
    for (int t = 0; t < 4; ++t) {
        float xv = xp[(size_t)t * BCN];
        float h = v + (xv - v) * 0.5f;                  // v + (x - v)/tau, tau = 2
        bool s = (h >= 1.0f);
        unsigned long long m = __ballot(s);
        v = s ? 0.f : h;
        if (lane == 0) xm[(((size_t)t * 16 + b) * 16 + g) * 384 + c] = m;
    }
}

// ---------------- K1b: 64x64 bit transpose: n-packed -> c-packed ----------------
// wave = (t,b,g,cg); lane holds row c = cg*64+lane; 64 ballots produce column words.
__global__ __launch_bounds__(256) void k1b_transpose(const unsigned long long* __restrict__ xm,
                                                     unsigned long long* __restrict__ xmT) {
    int wid  = (blockIdx.x * 256 + threadIdx.x) >> 6;   // 0..6143
    int lane = threadIdx.x & 63;
    int cg = wid % 6;
    int g  = (wid / 6) % 16;
    int tb = wid / 96;                                  // t*16 + b
    unsigned long long W = xm[((size_t)tb * 16 + g) * 384 + cg * 64 + lane];
    unsigned long long T = 0ull;
    #pragma unroll
    for (int k = 0; k < 64; ++k) {
        unsigned long long bk = __ballot((W >> k) & 1ull);  // bit c = spike(c, n=g*64+k)
        if (lane == k) T = bk;
    }
    xmT[((size_t)tb * 1024 + g * 64 + lane) * 6 + cg] = T;
}

// ---------------- K2: gather GEMM1 + BN + q-LIF + attn mask (no LDS, no atomics) ---
// block = (b, 16-n tile); 384 threads; thread owns output channel o = tid.
// Masks are block-uniform -> scalar-pipe bit iteration driving coalesced wqT row loads;
// accumulation entirely in VGPRs; 4 t's gathered together for memory-level parallelism.
__global__ __launch_bounds__(384) void k2_qpath(const float* __restrict__ wqT,
                                                const float* __restrict__ qinv_,
                                                const float* __restrict__ qoff_,
                                                const unsigned long long* __restrict__ xmT,
                                                const unsigned char* __restrict__ ak,
                                                const unsigned char* __restrict__ av,
                                                unsigned long long* __restrict__ msT) {
    const int tid  = threadIdx.x;                // output channel o
    const int lane = tid & 63;
    const int w    = tid >> 6;                   // o-group 0..5
    const int bid  = blockIdx.x;
    const int nt   = bid & 63;                   // n-tile
    const int b    = bid >> 6;
    const float qi = qinv_[tid], qo = qoff_[tid];

    for (int nl = 0; nl < 16; ++nl) {
        const int n = nt * 16 + nl;
        unsigned long long m[4][6];
        #pragma unroll
        for (int t = 0; t < 4; ++t) {
            const unsigned long long* mp = xmT + ((size_t)(t * 16 + b) * 1024 + n) * 6;
            #pragma unroll
            for (int cg = 0; cg < 6; ++cg) m[t][cg] = mp[cg];
        }
        float acc[4] = {0.f, 0.f, 0.f, 0.f};
        #pragma unroll
        for (int t = 0; t < 4; ++t) {
            #pragma unroll
            for (int cg = 0; cg < 6; ++cg) {
                unsigned long long mm = m[t][cg];
                while (mm) {
                    int j = __builtin_ctzll(mm);
                    mm &= mm - 1;
                    acc[t] += wqT[(size_t)(cg * 64 + j) * 384 + tid];
                }
            }
        }
        float v = 0.f;
        #pragma unroll
        for (int t = 0; t < 4; ++t) {
            float qbn = acc[t] * qi + qo;
            float h = 0.5f * (v + qbn);          // v + (q - v)/2
            bool s = (h >= 1.0f);
            v = s ? 0.f : h;
            if (s) {                              // rare: attn-mask lookup only on q-spike
                size_t idx = ((size_t)((t * 16 + b) * 384 + tid) << 10) + n;
                s = (ak[idx] != 0) && (av[idx] != 0);
            }
            unsigned long long bw = __ballot(s);  // c-packed word for o-group w
            if (lane == 0)
                msT[((size_t)(t * 16 + b) * 1024 + n) * 6 + w] = bw;
        }
    }
}

// ---------------- K3: proj GEMM2 + bias + BN (gather-based, atomic-free) ----------
// block = (t, b, g); fast constant path when all 64 n-columns of this g have no spikes.
__global__ __launch_bounds__(384) void k3_proj(const float* __restrict__ wpT,
                                               const float* __restrict__ pinv_,
                                               const float* __restrict__ poff_,
                                               const float* __restrict__ bp,
                                               const float* __restrict__ c0,
                                               const unsigned long long* __restrict__ msT,
                                               float* __restrict__ out) {
    __shared__ unsigned int wflag[6];
    const int tid = threadIdx.x;
    const int bid = blockIdx.x;
    const int g = bid & 15, b = (bid >> 4) & 15, t = bid >> 8;
    const unsigned long long* mbase = msT + ((size_t)(t * 16 + b) * 1024 + g * 64) * 6;
    unsigned long long m = mbase[tid];           // 384 words: n-local = tid/6, cg = tid%6
    unsigned long long anyb = __ballot(m != 0ull);
    if ((tid & 63) == 0) wflag[tid >> 6] = (anyb != 0ull) ? 1u : 0u;
    __syncthreads();
    unsigned int any = wflag[0] | wflag[1] | wflag[2] | wflag[3] | wflag[4] | wflag[5];
    size_t obase = (size_t)(t * 16 + b) * 384;

    if (!any) {
        // all-zero GEMM2 input: out = bp*inv + off, coalesced float4 stores
        #pragma unroll
        for (int k = 0; k < 16; ++k) {
            int i = tid + k * 384;               // 6144 float4 units in the (384o x 64n) tile
            int o = i >> 4, n4 = i & 15;
            float vv = c0[o];
            float4* dst = (float4*)out + (obase + o) * 256 + g * 16 + n4;
            *dst = make_float4(vv, vv, vv, vv);
        }
        return;
    }
    // slow path (never taken on this input): per-n VGPR gather
    float pi = pinv_[tid], po = poff_[tid], bb = bp[tid];
    for (int nl = 0; nl < 64; ++nl) {
        float acc = 0.f;
        #pragma unroll
        for (int cg = 0; cg < 6; ++cg) {
            unsigned long long mm = mbase[nl * 6 + cg];
            while (mm) {
                int j = __builtin_ctzll(mm);
                mm &= mm - 1;
                acc += wpT[(size_t)(cg * 64 + j) * 384 + tid];
            }
        }
        out[(obase + tid) * 1024 + g * 64 + nl] = (acc + bb) * pi + po;
    }
}

extern "C" void kernel_launch(void* const* d_in, const int* in_sizes, int n_in,
                              void* d_out, int out_size, void* d_ws, size_t ws_size,
                              hipStream_t stream) {
    const float* x  = (const float*)d_in[0];
    const unsigned char* ak = (const unsigned char*)d_in[1];
    const unsigned char* av = (const unsigned char*)d_in[2];
    const float* wq = (const float*)d_in[3];
    const float* qg = (const float*)d_in[4];
    const float* qb = (const float*)d_in[5];
    const float* qm = (const float*)d_in[6];
    const float* qv = (const float*)d_in[7];
    const float* wp = (const float*)d_in[8];
    const float* bp = (const float*)d_in[9];
    const float* pg = (const float*)d_in[10];
    const float* pb = (const float*)d_in[11];
    const float* pm = (const float*)d_in[12];
    const float* pv = (const float*)d_in[13];
    char* ws = (char*)d_ws;
    float* out = (float*)d_out;

    hipLaunchKernelGGL(k0_transpose, dim3(1152), dim3(256), 0, stream, wq, wp, ws);
    hipLaunchKernelGGL(k0_consts, dim3(1), dim3(384), 0, stream,
                       qg, qb, qm, qv, pg, pb, pm, pv, bp, ws);
    hipLaunchKernelGGL(k1_lif, dim3(24576), dim3(256), 0, stream,
                       x, (unsigned long long*)(ws + XM_OFF));
    hipLaunchKernelGGL(k1b_transpose, dim3(1536), dim3(256), 0, stream,
                       (const unsigned long long*)(ws + XM_OFF),
                       (unsigned long long*)(ws + XMT_OFF));
    hipLaunchKernelGGL(k2_qpath, dim3(1024), dim3(384), 0, stream,
                       (const float*)(ws + WQT_OFF), (const float*)(ws + QINV_OFF),
                       (const float*)(ws + QOFF_OFF),
                       (const unsigned long long*)(ws + XMT_OFF), ak, av,
                       (unsigned long long*)(ws + MST_OFF));
    hipLaunchKernelGGL(k3_proj, dim3(1024), dim3(384), 0, stream,
                       (const float*)(ws + WPT_OFF), (const float*)(ws + PINV_OFF),
                       (const float*)(ws + POFF_OFF), bp, (const float*)(ws + C0_OFF),
                       (const unsigned long long*)(ws + MST_OFF), out);
}